// Round 7
// baseline (151.377 us; speedup 1.0000x reference)
//
#include <hip/hip_runtime.h>

// B=256, C=2048, H*W=128, NUM_CLASSES=10000
// Outputs (fp32, concat): logits[256*10000], logits[256*10000],
//                         neck_feat[256*2048], new_weight[256] (== 1.0 analytically)
// targets are dead.
//
// R7: GEMM = 625 single-wave blocks (16 W-rows each), zero LDS, zero barriers.
// A k-tiles read straight from L2 in a wave-local layout; W read exactly once.

#define OUT1_OFF (256 * 10000)
#define FEAT_OFF (2 * 256 * 10000)
#define NW_OFF   (2 * 256 * 10000 + 256 * 2048)

typedef __attribute__((ext_vector_type(4))) float f32x4;
typedef __attribute__((ext_vector_type(8))) short bf16x8;
typedef __attribute__((ext_vector_type(4))) unsigned int u32x4;

__device__ inline unsigned pk2bf(float lo, float hi) {
    unsigned a = __float_as_uint(lo), b = __float_as_uint(hi);
    unsigned ra = (a + 0x7FFFu + ((a >> 16) & 1u)) >> 16;
    unsigned rb = (b + 0x7FFFu + ((b >> 16) & 1u)) & 0xFFFF0000u;
    return ra | rb;
}

// ---------------------------------------------------------------------------
// Kernel 1 (pool): R2 structure (measured at BW roofline, ~36us). Only the
// ws A-layout changed: element (m=b, k=c) lives at 16B-chunk
//   chunk2 = (kt*64 + q*16 + r)*16 + mf,   byte 2*(k&7)
// with kt=k>>5, q=(k>>3)&3, r=m&15, mf=m>>4. This makes a wave's 16 m-frag
// chunks for fixed (kt, lane=q*16+r) CONTIGUOUS (one base + imm offsets).
// ---------------------------------------------------------------------------
__global__ __launch_bounds__(256) void pool_kernel(
    const float* __restrict__ f, float* __restrict__ out,
    unsigned int* __restrict__ wsA32) {
    int tid = threadIdx.x;
    int g = tid >> 5;
    int l = tid & 31;
    int r0 = blockIdx.x * 16 + g * 2;  // rows r0, r0+1 (r0 even)
    const f32x4* s0 = (const f32x4*)(f + (size_t)r0 * 128);
    f32x4 v0 = s0[l];
    f32x4 v1 = s0[l + 32];
    float a = v0[0] + v0[1] + v0[2] + v0[3];
    float b = v1[0] + v1[1] + v1[2] + v1[3];
#pragma unroll
    for (int off = 16; off >= 1; off >>= 1) {
        a += __shfl_xor(a, off);
        b += __shfl_xor(b, off);
    }
    if (l == 0) {
        float m0 = a * (1.0f / 128.0f), m1 = b * (1.0f / 128.0f);
        float2 fv; fv.x = m0; fv.y = m1;
        *(float2*)&out[FEAT_OFF + r0] = fv;
        int bb = r0 >> 11, c = r0 & 2047;  // m=bb, k=c (c even)
        int kt = c >> 5, q = (c >> 3) & 3, rr = bb & 15, mf = bb >> 4;
        int chunk2 = (kt * 64 + q * 16 + rr) * 16 + mf;
        wsA32[chunk2 * 4 + ((c & 7) >> 1)] = pk2bf(m0, m1);
    }
    if (blockIdx.x == 0) out[NW_OFF + tid] = 1.0f;
}

// ---------------------------------------------------------------------------
// Kernel 2 (GEMM): 625 blocks x 64 threads (1 wave). Block owns W rows
// [bn0, bn0+16) (10000 = 625*16, no edge). Per k-step (K=32): 16 A-frag
// loads (contiguous 256B/lane from ws layout), 2 W f32x4 loads, 4 pk2bf,
// 16 MFMA 16x16x32 into acc[16] (covers all M=256). Depth-2 X/Y register
// pipeline; no LDS, no barriers; compiler inserts precise waits.
// ---------------------------------------------------------------------------
__global__ __launch_bounds__(64) void gemm_kernel(
    const u32x4* __restrict__ A16, const float* __restrict__ W,
    float* __restrict__ out) {
    int lane = threadIdx.x;            // 0..63
    int r = lane & 15, q = lane >> 4;  // B row-in-tile, k-quad
    int bn0 = blockIdx.x * 16;

    const u32x4* pa = A16 + lane * 16;  // + kt*1024 + mf
    const f32x4* pw = (const f32x4*)(W + (size_t)(bn0 + r) * 2048) + q * 2;  // + kt*8

    f32x4 acc[16];
#pragma unroll
    for (int i = 0; i < 16; ++i) acc[i] = (f32x4){0.f, 0.f, 0.f, 0.f};

    u32x4 Xa0, Xa1, Xa2, Xa3, Xa4, Xa5, Xa6, Xa7,
          Xa8, Xa9, Xa10, Xa11, Xa12, Xa13, Xa14, Xa15;
    u32x4 Ya0, Ya1, Ya2, Ya3, Ya4, Ya5, Ya6, Ya7,
          Ya8, Ya9, Ya10, Ya11, Ya12, Ya13, Ya14, Ya15;
    f32x4 Xw0, Xw1, Yw0, Yw1;

#define ISSUE(S, kt)                                    \
    {                                                   \
        const u32x4* p = pa + (kt) * 1024;              \
        S##w0 = pw[(kt) * 8];                           \
        S##w1 = pw[(kt) * 8 + 1];                       \
        S##a0 = p[0];   S##a1 = p[1];                   \
        S##a2 = p[2];   S##a3 = p[3];                   \
        S##a4 = p[4];   S##a5 = p[5];                   \
        S##a6 = p[6];   S##a7 = p[7];                   \
        S##a8 = p[8];   S##a9 = p[9];                   \
        S##a10 = p[10]; S##a11 = p[11];                 \
        S##a12 = p[12]; S##a13 = p[13];                 \
        S##a14 = p[14]; S##a15 = p[15];                 \
    }

#define MF(mf, a_, bv) \
    acc[mf] = __builtin_amdgcn_mfma_f32_16x16x32_bf16(*(bf16x8*)&a_, bv, acc[mf], 0, 0, 0)

#define COMPUTE(S)                                                 \
    {                                                              \
        u32x4 t;                                                   \
        t.x = pk2bf(S##w0[0], S##w0[1]);                           \
        t.y = pk2bf(S##w0[2], S##w0[3]);                           \
        t.z = pk2bf(S##w1[0], S##w1[1]);                           \
        t.w = pk2bf(S##w1[2], S##w1[3]);                           \
        bf16x8 bv = *(bf16x8*)&t;                                  \
        MF(0, S##a0, bv);   MF(1, S##a1, bv);                      \
        MF(2, S##a2, bv);   MF(3, S##a3, bv);                      \
        MF(4, S##a4, bv);   MF(5, S##a5, bv);                      \
        MF(6, S##a6, bv);   MF(7, S##a7, bv);                      \
        MF(8, S##a8, bv);   MF(9, S##a9, bv);                      \
        MF(10, S##a10, bv); MF(11, S##a11, bv);                    \
        MF(12, S##a12, bv); MF(13, S##a13, bv);                    \
        MF(14, S##a14, bv); MF(15, S##a15, bv);                    \
    }

    ISSUE(X, 0);
    ISSUE(Y, 1);
    for (int kt = 0; kt < 62; kt += 2) {
        COMPUTE(X);
        ISSUE(X, kt + 2);
        COMPUTE(Y);
        ISSUE(Y, kt + 3);
    }
    COMPUTE(X);
    COMPUTE(Y);

    // ---- epilogue: C and C*SCALE (SCALE=1); n = bn0 + r, m = mf*16+q*4+j ----
#pragma unroll
    for (int mf = 0; mf < 16; ++mf) {
#pragma unroll
        for (int j = 0; j < 4; ++j) {
            size_t off = (size_t)(mf * 16 + q * 4 + j) * 10000 + bn0 + r;
            float v = acc[mf][j];
            out[off] = v;
            out[OUT1_OFF + off] = v;
        }
    }
#undef ISSUE
#undef MF
#undef COMPUTE
}

extern "C" void kernel_launch(void* const* d_in, const int* in_sizes, int n_in,
                              void* d_out, int out_size, void* d_ws, size_t ws_size,
                              hipStream_t stream) {
    const float* feats = (const float*)d_in[0];
    // d_in[1] = targets (int32) — dead (new_weight == ones analytically)
    const float* weight = (const float*)d_in[2];
    float* out = (float*)d_out;

    pool_kernel<<<32768, 256, 0, stream>>>(feats, out, (unsigned int*)d_ws);
    gemm_kernel<<<625, 64, 0, stream>>>((const u32x4*)d_ws, weight, out);
}

// Round 8
// 113.011 us; speedup vs baseline: 1.3395x; 1.3395x over previous
//
#include <hip/hip_runtime.h>

// B=256, C=2048, H*W=128, NUM_CLASSES=10000
// Outputs (fp32, concat): logits[256*10000], logits[256*10000],
//                         neck_feat[256*2048], new_weight[256] (== 1.0 analytically)
// targets are dead.
//
// R8: prep kernel = pool (R2 structure, proven ~36us) + W fp32->bf16 convert
// into B-fragment-major ws (pure stream). GEMM then DMA-stages BOTH operands
// (global_load_lds, contiguous 1KB/wave-instr granules), BM=128/BN=64,
// 314 blocks (2/CU), no PACK, counted vmcnt(3), 1 barrier/kt.

#define OUT1_OFF (256 * 10000)
#define FEAT_OFF (2 * 256 * 10000)
#define NW_OFF   (2 * 256 * 10000 + 256 * 2048)

typedef __attribute__((ext_vector_type(4))) float f32x4;
typedef __attribute__((ext_vector_type(8))) short bf16x8;
typedef __attribute__((ext_vector_type(4))) unsigned int u32x4;

__device__ inline unsigned pk2bf(float lo, float hi) {
    unsigned a = __float_as_uint(lo), b = __float_as_uint(hi);
    unsigned ra = (a + 0x7FFFu + ((a >> 16) & 1u)) >> 16;
    unsigned rb = (b + 0x7FFFu + ((b >> 16) & 1u)) & 0xFFFF0000u;
    return ra | rb;
}

__device__ inline void gload_lds16(const void* g, void* l) {
    __builtin_amdgcn_global_load_lds(
        (const __attribute__((address_space(1))) void*)g,
        (__attribute__((address_space(3))) void*)l, 16, 0, 0);
}

// ---------------------------------------------------------------------------
// Kernel 1 (prep): blocks [0,32768) = pool (EXACT R2 structure/layout);
// blocks [32768, 33393) = wconv: W fp32 -> bf16 fragment-major ws.
//   A-chunk(m,k)=((m>>4)*256+(k>>3))*16+(m&15), word (k&7)>>1  (wsA)
//   B-chunk(n,k)=((n>>4)*256+(k>>3))*16+(n&15)                 (wsB)
// wconv block: 16 rows; per iter kc writes 4KB contiguous; reads 128B/row runs.
// ---------------------------------------------------------------------------
__global__ __launch_bounds__(256) void prep_kernel(
    const float* __restrict__ f, const float* __restrict__ W,
    float* __restrict__ out, unsigned int* __restrict__ wsA32,
    u32x4* __restrict__ wsB) {
    int bid = blockIdx.x;
    int tid = threadIdx.x;
    if (bid < 32768) {
        int g = tid >> 5;
        int l = tid & 31;
        int r0 = bid * 16 + g * 2;  // rows r0, r0+1 (r0 even)
        const f32x4* s0 = (const f32x4*)(f + (size_t)r0 * 128);
        f32x4 v0 = s0[l];
        f32x4 v1 = s0[l + 32];
        float a = v0[0] + v0[1] + v0[2] + v0[3];
        float b = v1[0] + v1[1] + v1[2] + v1[3];
#pragma unroll
        for (int off = 16; off >= 1; off >>= 1) {
            a += __shfl_xor(a, off);
            b += __shfl_xor(b, off);
        }
        if (l == 0) {
            float m0 = a * (1.0f / 128.0f), m1 = b * (1.0f / 128.0f);
            float2 fv; fv.x = m0; fv.y = m1;
            *(float2*)&out[FEAT_OFF + r0] = fv;
            int bb = r0 >> 11, c = r0 & 2047;
            int chunk = ((bb >> 4) * 256 + (c >> 3)) * 16 + (bb & 15);
            wsA32[chunk * 4 + ((c & 7) >> 1)] = pk2bf(m0, m1);
        }
        if (bid == 0) out[NW_OFF + tid] = 1.0f;
    } else {
        int nb = bid - 32768;      // 0..624
        int n0 = nb * 16;
        int r = tid & 15, kq = tid >> 4;  // kq 0..15
        const f32x4* src = (const f32x4*)(W + (size_t)(n0 + r) * 2048) + kq * 2;
        u32x4* dst = wsB + ((size_t)(n0 >> 4) * 256 + kq) * 16 + r;
#pragma unroll
        for (int kc = 0; kc < 16; ++kc) {
            f32x4 a = src[kc * 32], b = src[kc * 32 + 1];
            u32x4 p;
            p.x = pk2bf(a[0], a[1]);
            p.y = pk2bf(a[2], a[3]);
            p.z = pk2bf(b[0], b[1]);
            p.w = pk2bf(b[2], b[3]);
            dst[kc * 256] = p;
        }
    }
}

// ---------------------------------------------------------------------------
// Kernel 2 (GEMM): logits = A(256x2048 bf16) * Wbf16(10000x2048)^T, both
// operands DMA-staged from fragment-major ws. BM=128, BN=64, BK=64.
// Grid (2,157) = 314 blocks x 512 thr (8 waves 4m x 2n, wave tile 32x32).
// LDS 72 KB (3-buf As 16K + Bs 8K) -> 2 blocks/CU. Per thread per kt:
// 2 A-DMA + 1 B-DMA (each 1KB contiguous per wave-instr). Depth-2,
// vmcnt(3), one s_barrier per kt. No VALU staging at all.
// ---------------------------------------------------------------------------
__global__ __launch_bounds__(512) void gemm_kernel(
    const u32x4* __restrict__ A16, const u32x4* __restrict__ B16,
    float* __restrict__ out) {
    __shared__ u32x4 As[3][1024];  // 16 KB per buf
    __shared__ u32x4 Bs[3][512];   // 8 KB per buf -> 72 KB total

    int tid = threadIdx.x;
    int mh = blockIdx.x;          // 0..1
    int n0 = blockIdx.y * 64;     // 0..156 (last tile: cols 9984..10047, predicated)
    int wid = tid >> 6, lane = tid & 63;
    int wm = wid >> 1, wn = wid & 1;
    int r = lane & 15, kqu = lane >> 4;

    // A chunks: ci = tid + i*512 -> mf=ci>>7 (0..7), kg=(ci>>4)&7, r=ci&15
    const u32x4* ga[2];
#pragma unroll
    for (int i = 0; i < 2; ++i) {
        int ci = tid + i * 512;
        ga[i] = A16 + (((mh * 8 + (ci >> 7)) * 256 + ((ci >> 4) & 7)) * 16 + (ci & 15));
    }
    // B chunk: ci = tid -> nf=tid>>7, kg=(tid>>4)&7, r=tid&15; per-wave 1KB runs
    const u32x4* gb = B16 + ((size_t)(n0 >> 4) * 4096 + (tid >> 7) * 4096 + (tid & 127));

    f32x4 acc[2][2];
#pragma unroll
    for (int i = 0; i < 2; ++i)
#pragma unroll
        for (int j = 0; j < 2; ++j) acc[i][j] = (f32x4){0.f, 0.f, 0.f, 0.f};

#define STAGE(kt, buf)                                                \
    {                                                                 \
        _Pragma("unroll") for (int i = 0; i < 2; ++i)                 \
            gload_lds16(ga[i] + (kt) * 128, &As[buf][tid + i * 512]); \
        gload_lds16(gb + (kt) * 128, &Bs[buf][tid]);                  \
    }

    // ---- prologue: tiles 0 and 1 in flight ----
    STAGE(0, 0);
    STAGE(1, 1);
    asm volatile("s_waitcnt vmcnt(3)" ::: "memory");  // tile 0 landed
    __builtin_amdgcn_sched_barrier(0);
    __builtin_amdgcn_s_barrier();
    __builtin_amdgcn_sched_barrier(0);

    for (int kt = 0; kt < 32; ++kt) {
        int cur = kt % 3;
        if (kt <= 29) {
            int nx2 = (kt + 2) % 3;
            STAGE(kt + 2, nx2);
        }
#pragma unroll
        for (int ks = 0; ks < 2; ++ks) {
            int kcl = ks * 4 + kqu;
            bf16x8 av[2], bv[2];
#pragma unroll
            for (int i = 0; i < 2; ++i)
                av[i] = *(const bf16x8*)&As[cur][(wm * 2 + i) * 128 + kcl * 16 + r];
#pragma unroll
            for (int j = 0; j < 2; ++j)
                bv[j] = *(const bf16x8*)&Bs[cur][(wn * 2 + j) * 128 + kcl * 16 + r];
#pragma unroll
            for (int i = 0; i < 2; ++i)
#pragma unroll
                for (int j = 0; j < 2; ++j)
                    acc[i][j] = __builtin_amdgcn_mfma_f32_16x16x32_bf16(
                        av[i], bv[j], acc[i][j], 0, 0, 0);
        }
        if (kt <= 29) { asm volatile("s_waitcnt vmcnt(3)" ::: "memory"); }
        else          { asm volatile("s_waitcnt vmcnt(0)" ::: "memory"); }
        __builtin_amdgcn_sched_barrier(0);
        if (kt < 31) {
            __builtin_amdgcn_s_barrier();
        }
        __builtin_amdgcn_sched_barrier(0);
    }

    // ---- epilogue: C and C*SCALE (SCALE=1) ----
#pragma unroll
    for (int i = 0; i < 2; ++i)
#pragma unroll
        for (int j = 0; j < 2; ++j) {
            int n = n0 + (wn * 2 + j) * 16 + r;
            if (n < 10000) {
                int mbase = mh * 128 + (wm * 2 + i) * 16 + kqu * 4;
#pragma unroll
                for (int q = 0; q < 4; ++q) {
                    float v = acc[i][j][q];
                    size_t off = (size_t)(mbase + q) * 10000 + n;
                    out[off] = v;
                    out[OUT1_OFF + off] = v;
                }
            }
        }
#undef STAGE
}

extern "C" void kernel_launch(void* const* d_in, const int* in_sizes, int n_in,
                              void* d_out, int out_size, void* d_ws, size_t ws_size,
                              hipStream_t stream) {
    const float* feats = (const float*)d_in[0];
    // d_in[1] = targets (int32) — dead (new_weight == ones analytically)
    const float* weight = (const float*)d_in[2];
    float* out = (float*)d_out;
    unsigned int* wsA = (unsigned int*)d_ws;                       // 1 MB
    u32x4* wsB = (u32x4*)((char*)d_ws + (2u << 20));               // ~41 MB

    prep_kernel<<<33393, 256, 0, stream>>>(feats, weight, out, wsA, wsB);
    gemm_kernel<<<dim3(2, 157), 512, 0, stream>>>((const u32x4*)wsA, wsB, out);
}